// Round 6
// baseline (493.321 us; speedup 1.0000x reference)
//
#include <hip/hip_runtime.h>
#include <hip/hip_bf16.h>

// out[M,N] = x[M,K] @ W[N,K]^T + 2.0 * (x @ A[R,K]^T) @ B[N,R]^T
//          = x @ (W + 2.0 * B@A)^T
// M=16384, N=2048, K=2048, R=64.  fp32 in/out; bf16 MFMA internally.
// R4: cvt pass eliminated — fp32->bf16 conversion fused into GEMM A-staging
// (reg-staged A + ds_write_b128; B stays on global_load_lds).

typedef short short8 __attribute__((ext_vector_type(8)));
typedef float f32x4 __attribute__((ext_vector_type(4)));

#define BM 128
#define BN 128
#define BK 32

__device__ __forceinline__ unsigned short f2bf(float f) {
  unsigned u = __float_as_uint(f);
  u += 0x7fff + ((u >> 16) & 1);   // round-to-nearest-even
  return (unsigned short)(u >> 16);
}

// ---------------- pass 1: W_eff = bf16(W + scaling * B@A) ----------------
// grid (K/256, N/16) = 1024 blocks; one ic-chunk per block (R3 fix, ~40 us).
__global__ __launch_bounds__(256) void weff_kernel(const float* __restrict__ W,
                                                   const float* __restrict__ Alora,
                                                   const float* __restrict__ Blora,
                                                   unsigned short* __restrict__ Weff,
                                                   int N, int K, int R, float scaling) {
  __shared__ float Bs[16][64];
  int t = threadIdx.x;
  int ob = blockIdx.y * 16;
  int i = blockIdx.x * 256 + t;
  for (int j = t; j < 16 * 64; j += 256)
    Bs[j >> 6][j & 63] = Blora[(ob + (j >> 6)) * R + (j & 63)];
  __syncthreads();
  float acc[16];
#pragma unroll
  for (int o = 0; o < 16; ++o) acc[o] = 0.f;
#pragma unroll 8
  for (int r = 0; r < 64; ++r) {
    float av = Alora[r * K + i];
#pragma unroll
    for (int o = 0; o < 16; ++o) acc[o] = fmaf(Bs[o][r], av, acc[o]);
  }
#pragma unroll
  for (int o = 0; o < 16; ++o) {
    float w = W[(size_t)(ob + o) * K + i];
    Weff[(size_t)(ob + o) * K + i] = f2bf(w + scaling * acc[o]);
  }
}

// ---------------- pass 2: fused cvt+GEMM, C = bf16(X) @ Wb^T ----------------
#define GLOAD_LDS16(g, l)                                                        \
  __builtin_amdgcn_global_load_lds((const __attribute__((address_space(1))) void*)(g), \
                                   (__attribute__((address_space(3))) void*)(l), 16, 0, 0)

__global__ __launch_bounds__(256) void gemm_fused_kernel(const float* __restrict__ X,
                                                         const unsigned short* __restrict__ Wb,
                                                         float* __restrict__ out,
                                                         int M, int N, int K) {
  __shared__ __align__(16) unsigned short As[BM * BK];
  __shared__ __align__(16) unsigned short Bsh[BN * BK];

  int t = threadIdx.x;
  int lane = t & 63;
  int wave = t >> 6;
  int wr = wave >> 1, wc = wave & 1;

  // T1: XCD-aware bijective swizzle (nwg=2048, %8==0).
  int nwg = gridDim.x;
  int cpx = nwg >> 3;
  int swz = (blockIdx.x & 7) * cpx + (blockIdx.x >> 3);
  int nbn = N / BN;
  int bm = swz / nbn, bn = swz % nbn;

  f32x4 acc[4][4];
  f32x4 z = {0.f, 0.f, 0.f, 0.f};
#pragma unroll
  for (int m = 0; m < 4; ++m)
#pragma unroll
    for (int n = 0; n < 4; ++n) acc[m][n] = z;

  // staging geometry: thread t covers 8 elems (row t/4, col (t%4)*8) and the
  // same at row+64. B: global_load_lds 16B. A: float4 x2 -> cvt_pk -> ds_write_b128.
  int srow = t >> 2;
  int scol = (t & 3) * 8;
  const float* Ag = X + (size_t)(bm * BM + srow) * K + scol;
  const unsigned short* Bg = Wb + (size_t)(bn * BN + srow) * K + scol;
  int ldsOff = t * 8;  // elements (16B per thread)

  // MFMA fragment read offsets (elements): row stride BK
  int aoff = (wr * 64 + (lane & 15)) * BK + (lane >> 4) * 8;
  int boff = (wc * 64 + (lane & 15)) * BK + (lane >> 4) * 8;

  for (int k0 = 0; k0 < K; k0 += BK) {
    // issue B's async loads first so they fly while A round-trips registers
    GLOAD_LDS16(Bg + k0,                  Bsh + ldsOff);
    GLOAD_LDS16(Bg + (size_t)64 * K + k0, Bsh + ldsOff + 2048);

    float4 a0 = *(const float4*)(Ag + k0);
    float4 a1 = *(const float4*)(Ag + k0 + 4);
    float4 a2 = *(const float4*)(Ag + (size_t)64 * K + k0);
    float4 a3 = *(const float4*)(Ag + (size_t)64 * K + k0 + 4);

    union { short8 s; __hip_bfloat162 h[4]; } u0, u1;
    u0.h[0] = __float22bfloat162_rn(make_float2(a0.x, a0.y));
    u0.h[1] = __float22bfloat162_rn(make_float2(a0.z, a0.w));
    u0.h[2] = __float22bfloat162_rn(make_float2(a1.x, a1.y));
    u0.h[3] = __float22bfloat162_rn(make_float2(a1.z, a1.w));
    u1.h[0] = __float22bfloat162_rn(make_float2(a2.x, a2.y));
    u1.h[1] = __float22bfloat162_rn(make_float2(a2.z, a2.w));
    u1.h[2] = __float22bfloat162_rn(make_float2(a3.x, a3.y));
    u1.h[3] = __float22bfloat162_rn(make_float2(a3.z, a3.w));
    *(short8*)(As + ldsOff)        = u0.s;  // ds_write_b128
    *(short8*)(As + ldsOff + 2048) = u1.s;

    __syncthreads();

    short8 af[4], bf[4];
#pragma unroll
    for (int m = 0; m < 4; ++m) af[m] = *(const short8*)(As + aoff + m * 16 * BK);
#pragma unroll
    for (int n = 0; n < 4; ++n) bf[n] = *(const short8*)(Bsh + boff + n * 16 * BK);
#pragma unroll
    for (int m = 0; m < 4; ++m)
#pragma unroll
      for (int n = 0; n < 4; ++n)
        acc[m][n] = __builtin_amdgcn_mfma_f32_16x16x32_bf16(af[m], bf[n], acc[m][n], 0, 0, 0);
    __syncthreads();
  }

  // epilogue: C/D layout col = lane&15, row = (lane>>4)*4 + j  [m89/m91]
  int orow0 = bm * BM + wr * 64 + ((lane >> 4) << 2);
  int ocol0 = bn * BN + wc * 64 + (lane & 15);
#pragma unroll
  for (int m = 0; m < 4; ++m)
#pragma unroll
    for (int n = 0; n < 4; ++n) {
      size_t base = (size_t)(orow0 + m * 16) * N + (ocol0 + n * 16);
#pragma unroll
      for (int j = 0; j < 4; ++j) out[base + (size_t)j * N] = acc[m][n][j];
    }
}

extern "C" void kernel_launch(void* const* d_in, const int* in_sizes, int n_in,
                              void* d_out, int out_size, void* d_ws, size_t ws_size,
                              hipStream_t stream) {
  const float* x  = (const float*)d_in[0];
  const float* W  = (const float*)d_in[1];
  const float* Al = (const float*)d_in[2];
  const float* Bl = (const float*)d_in[3];
  float* out = (float*)d_out;

  const int K = 2048;
  const long long M = (long long)in_sizes[0] / K;  // 16384
  const int N = in_sizes[1] / K;                   // 2048
  const int R = in_sizes[2] / K;                   // 64

  unsigned short* weff = (unsigned short*)d_ws;    // N*K*2 = 8.4 MB of ws

  weff_kernel<<<dim3(K / 256, N / 16), 256, 0, stream>>>(W, Al, Bl, weff, N, K, R, 2.0f);
  gemm_fused_kernel<<<(N / BN) * (int)(M / BM), 256, 0, stream>>>(x, weff, out, (int)M, N, K);
}

// Round 7
// 395.935 us; speedup vs baseline: 1.2460x; 1.2460x over previous
//
#include <hip/hip_runtime.h>
#include <hip/hip_bf16.h>

// out[M,N] = x @ (W + 2*B@A)^T.  M=16384, N=2048, K=2048, R=64.
// R7: 256x256 tile, BK=32, 4-deep LDS ring, counted vmcnt(8), XOR-swizzled LDS
// (both-sides: pre-swizzled global source + swizzled ds_read), setprio, 1 barrier/K-step.
// Separate cvt pass restored (R4 fusion regressed gemm by +100us).

typedef short short8 __attribute__((ext_vector_type(8)));
typedef float f32x4 __attribute__((ext_vector_type(4)));

#define TK 32
#define SLOT_BYTES 32768  // A half: 16KB + B half: 16KB per K-step slot

__device__ __forceinline__ unsigned short f2bf(float f) {
  unsigned u = __float_as_uint(f);
  u += 0x7fff + ((u >> 16) & 1);
  return (unsigned short)(u >> 16);
}

// ---------------- pass 1: x fp32 -> bf16 (~40us, BW-bound) ----------------
__global__ __launch_bounds__(256) void cvt_x_kernel(const float* __restrict__ x,
                                                    unsigned short* __restrict__ xb,
                                                    long long n) {
  long long idx = ((long long)blockIdx.x * 256 + threadIdx.x) * 8;
  long long stride = (long long)gridDim.x * 256 * 8;
  for (; idx < n; idx += stride) {
    float4 v0 = *(const float4*)(x + idx);
    float4 v1 = *(const float4*)(x + idx + 4);
    short8 o;
    o[0] = (short)f2bf(v0.x); o[1] = (short)f2bf(v0.y);
    o[2] = (short)f2bf(v0.z); o[3] = (short)f2bf(v0.w);
    o[4] = (short)f2bf(v1.x); o[5] = (short)f2bf(v1.y);
    o[6] = (short)f2bf(v1.z); o[7] = (short)f2bf(v1.w);
    *(short8*)(xb + idx) = o;
  }
}

// ---------------- pass 2: W_eff = bf16(W + scaling * B@A) ----------------
__global__ __launch_bounds__(256) void weff_kernel(const float* __restrict__ W,
                                                   const float* __restrict__ Alora,
                                                   const float* __restrict__ Blora,
                                                   unsigned short* __restrict__ Weff,
                                                   int N, int K, int R, float scaling) {
  __shared__ float Bs[16][64];
  int t = threadIdx.x;
  int ob = blockIdx.y * 16;
  int i = blockIdx.x * 256 + t;
  for (int j = t; j < 16 * 64; j += 256)
    Bs[j >> 6][j & 63] = Blora[(ob + (j >> 6)) * R + (j & 63)];
  __syncthreads();
  float acc[16];
#pragma unroll
  for (int o = 0; o < 16; ++o) acc[o] = 0.f;
#pragma unroll 8
  for (int r = 0; r < 64; ++r) {
    float av = Alora[r * K + i];
#pragma unroll
    for (int o = 0; o < 16; ++o) acc[o] = fmaf(Bs[o][r], av, acc[o]);
  }
#pragma unroll
  for (int o = 0; o < 16; ++o) {
    float w = W[(size_t)(ob + o) * K + i];
    Weff[(size_t)(ob + o) * K + i] = f2bf(w + scaling * acc[o]);
  }
}

// ---------------- pass 3: 256^2-tile pipelined bf16 GEMM ----------------
#define GLOAD_LDS16(g, l)                                                        \
  __builtin_amdgcn_global_load_lds((const __attribute__((address_space(1))) void*)(g), \
                                   (__attribute__((address_space(3))) void*)(l), 16, 0, 0)

// XOR swizzle: content at LDS byte b is the element at linear pos b ^ (((b>>7)&7)<<4).
// Involution (XOR bits 4-6 keyed by bits 7-9). Reader: addr = lin ^ (((lin>>7)&7)<<4);
// for frag reads the key is lane-constant: ((lane&15)>>1)&7, so addr = base + fm*1024.

__global__ __launch_bounds__(512, 2) void gemm256_kernel(const unsigned short* __restrict__ Xb,
                                                         const unsigned short* __restrict__ Wb,
                                                         float* __restrict__ out,
                                                         int M, int N, int K) {
  __shared__ __align__(16) char lds[4 * SLOT_BYTES];  // 128 KB ring

  const int t = threadIdx.x;
  const int lane = t & 63;
  const int w = t >> 6;
  const int wr = w >> 2, wc = w & 3;   // 2 x 4 wave grid; wave tile 128x64

  // T1: XCD-aware bijective swizzle (nwg=512, %8==0 -> simple variant ok)
  const int nwg = gridDim.x;
  const int cpx = nwg >> 3;
  const int swz = (blockIdx.x & 7) * cpx + (blockIdx.x >> 3);
  const int nbn = N >> 8;
  const int bm = swz / nbn, bn = swz % nbn;

  f32x4 acc[8][4];
  const f32x4 z = {0.f, 0.f, 0.f, 0.f};
#pragma unroll
  for (int i = 0; i < 8; ++i)
#pragma unroll
    for (int j = 0; j < 4; ++j) acc[i][j] = z;

  // ---- staging constants (inverse-swizzled global source, linear LDS dest) ----
  const int vs = (t >> 3) & 7;
  const int p0 = (t * 16) ^ (vs << 4);   // linear pos for dest byte t*16
  const int sm = p0 >> 6;                // source row (0..127) within half
  const int sk = ((p0 >> 4) & 3) * 8;    // source k offset (elems)
  const unsigned short* gA0 = Xb + (size_t)(bm * 256 + sm) * K + sk;
  const unsigned short* gB0 = Wb + (size_t)(bn * 256 + sm) * K + sk;

#define STAGE(SLOT, KOFF)                                                   \
  { char* la_ = lds + (SLOT) * SLOT_BYTES;                                  \
    GLOAD_LDS16(gA0 + (KOFF),                   la_ + t * 16);              \
    GLOAD_LDS16(gA0 + (size_t)128 * K + (KOFF), la_ + 8192 + t * 16);       \
    GLOAD_LDS16(gB0 + (KOFF),                   la_ + 16384 + t * 16);      \
    GLOAD_LDS16(gB0 + (size_t)128 * K + (KOFF), la_ + 24576 + t * 16); }

  // ---- frag read bases (swizzled) ----
  const int lane15 = lane & 15, ksl = lane >> 4;
  const int vr = (lane15 >> 1) & 7;
  const int abase = (((wr * 128 + lane15) * 64) + ksl * 16) ^ (vr << 4);
  const int bbase = 16384 + (((((wc * 64) + lane15) * 64) + ksl * 16) ^ (vr << 4));

#define PHASE_BODY(SLOT)                                                    \
  { char* lp_ = lds + (SLOT) * SLOT_BYTES;                                  \
    short8 af[8], bfr[4];                                                   \
    _Pragma("unroll") for (int i = 0; i < 8; ++i)                           \
      af[i] = *(const short8*)(lp_ + abase + i * 1024);                     \
    _Pragma("unroll") for (int j = 0; j < 4; ++j)                           \
      bfr[j] = *(const short8*)(lp_ + bbase + j * 1024);                    \
    __builtin_amdgcn_s_setprio(1);                                          \
    _Pragma("unroll") for (int i = 0; i < 8; ++i)                           \
      _Pragma("unroll") for (int j = 0; j < 4; ++j)                         \
        acc[i][j] = __builtin_amdgcn_mfma_f32_16x16x32_bf16(af[i], bfr[j],  \
                                                            acc[i][j], 0, 0, 0); \
    __builtin_amdgcn_s_setprio(0); }

#define WAITBAR(NSTR)                                                       \
  asm volatile("s_waitcnt vmcnt(" NSTR ")" ::: "memory");                   \
  __builtin_amdgcn_s_barrier();                                             \
  __builtin_amdgcn_sched_barrier(0);

  const int NT = K / TK;  // 64 K-steps
  // prologue: 3 K-step tiles in flight
  STAGE(0, 0)
  STAGE(1, TK)
  STAGE(2, 2 * TK)

  for (int u = 0; u < NT - 3; ++u) {
    WAITBAR("8")                      // drain tile u (keeps u+1,u+2 in flight)
    STAGE((u + 3) & 3, (u + 3) * TK)  // writes slot (u-1)&3: reads done pre-barrier
    PHASE_BODY(u & 3)
  }
  WAITBAR("8") PHASE_BODY((NT - 3) & 3)
  WAITBAR("4") PHASE_BODY((NT - 2) & 3)
  WAITBAR("0") PHASE_BODY((NT - 1) & 3)

  // epilogue: C/D layout col = lane&15, row = (lane>>4)*4 + j
  const int orow0 = bm * 256 + wr * 128 + ksl * 4;
  const int ocol0 = bn * 256 + wc * 64 + lane15;
#pragma unroll
  for (int i = 0; i < 8; ++i)
#pragma unroll
    for (int j = 0; j < 4; ++j) {
      size_t base = (size_t)(orow0 + i * 16) * N + (ocol0 + j * 16);
#pragma unroll
      for (int q = 0; q < 4; ++q) out[base + (size_t)q * N] = acc[i][j][q];
    }
}

extern "C" void kernel_launch(void* const* d_in, const int* in_sizes, int n_in,
                              void* d_out, int out_size, void* d_ws, size_t ws_size,
                              hipStream_t stream) {
  const float* x  = (const float*)d_in[0];
  const float* W  = (const float*)d_in[1];
  const float* Al = (const float*)d_in[2];
  const float* Bl = (const float*)d_in[3];
  float* out = (float*)d_out;

  const int K = 2048;
  const long long M = (long long)in_sizes[0] / K;  // 16384
  const int N = in_sizes[1] / K;                   // 2048
  const int R = in_sizes[2] / K;                   // 64

  unsigned short* xb   = (unsigned short*)d_ws;
  unsigned short* weff = xb + (size_t)M * K;       // (M*K + N*K)*2 = ~76 MB ws

  cvt_x_kernel<<<2048, 256, 0, stream>>>(x, xb, (long long)M * K);
  weff_kernel<<<dim3(K / 256, N / 16), 256, 0, stream>>>(W, Al, Bl, weff, N, K, R, 2.0f);
  gemm256_kernel<<<(N / 256) * (int)(M / 256), 512, 0, stream>>>(xb, weff, out, (int)M, N, K);
}

// Round 9
// 389.565 us; speedup vs baseline: 1.2663x; 1.0164x over previous
//
#include <hip/hip_runtime.h>
#include <hip/hip_bf16.h>

// out[M,N] = x @ (W + 2*B@A)^T.  M=16384, N=2048, K=2048, R=64.
// R8: R7 + register double-buffered fragments — ds_reads for tile u overlap
// MFMAs for tile u-1 (DS pipe || matrix pipe). lgkmcnt(0) folded into the
// per-iter waitcnt; slot reuse stays race-free. 2-step static unroll.

typedef short short8 __attribute__((ext_vector_type(8)));
typedef float f32x4 __attribute__((ext_vector_type(4)));

#define TK 32
#define SLOT_BYTES 32768

__device__ __forceinline__ unsigned short f2bf(float f) {
  unsigned u = __float_as_uint(f);
  u += 0x7fff + ((u >> 16) & 1);
  return (unsigned short)(u >> 16);
}

// ---------------- pass 1: x fp32 -> bf16 ----------------
__global__ __launch_bounds__(256) void cvt_x_kernel(const float* __restrict__ x,
                                                    unsigned short* __restrict__ xb,
                                                    long long n) {
  long long idx = ((long long)blockIdx.x * 256 + threadIdx.x) * 8;
  long long stride = (long long)gridDim.x * 256 * 8;
  for (; idx < n; idx += stride) {
    float4 v0 = *(const float4*)(x + idx);
    float4 v1 = *(const float4*)(x + idx + 4);
    short8 o;
    o[0] = (short)f2bf(v0.x); o[1] = (short)f2bf(v0.y);
    o[2] = (short)f2bf(v0.z); o[3] = (short)f2bf(v0.w);
    o[4] = (short)f2bf(v1.x); o[5] = (short)f2bf(v1.y);
    o[6] = (short)f2bf(v1.z); o[7] = (short)f2bf(v1.w);
    *(short8*)(xb + idx) = o;
  }
}

// ---------------- pass 2: W_eff = bf16(W + scaling * B@A) ----------------
__global__ __launch_bounds__(256) void weff_kernel(const float* __restrict__ W,
                                                   const float* __restrict__ Alora,
                                                   const float* __restrict__ Blora,
                                                   unsigned short* __restrict__ Weff,
                                                   int N, int K, int R, float scaling) {
  __shared__ float Bs[16][64];
  int t = threadIdx.x;
  int ob = blockIdx.y * 16;
  int i = blockIdx.x * 256 + t;
  for (int j = t; j < 16 * 64; j += 256)
    Bs[j >> 6][j & 63] = Blora[(ob + (j >> 6)) * R + (j & 63)];
  __syncthreads();
  float acc[16];
#pragma unroll
  for (int o = 0; o < 16; ++o) acc[o] = 0.f;
#pragma unroll 8
  for (int r = 0; r < 64; ++r) {
    float av = Alora[r * K + i];
#pragma unroll
    for (int o = 0; o < 16; ++o) acc[o] = fmaf(Bs[o][r], av, acc[o]);
  }
#pragma unroll
  for (int o = 0; o < 16; ++o) {
    float w = W[(size_t)(ob + o) * K + i];
    Weff[(size_t)(ob + o) * K + i] = f2bf(w + scaling * acc[o]);
  }
}

// ---------------- pass 3: 256^2-tile pipelined bf16 GEMM ----------------
#define GLOAD_LDS16(g, l)                                                        \
  __builtin_amdgcn_global_load_lds((const __attribute__((address_space(1))) void*)(g), \
                                   (__attribute__((address_space(3))) void*)(l), 16, 0, 0)

__global__ __launch_bounds__(512, 2) void gemm256_kernel(const unsigned short* __restrict__ Xb,
                                                         const unsigned short* __restrict__ Wb,
                                                         float* __restrict__ out,
                                                         int M, int N, int K) {
  __shared__ __align__(16) char lds[4 * SLOT_BYTES];  // 128 KB ring

  const int t = threadIdx.x;
  const int lane = t & 63;
  const int w = t >> 6;
  const int wr = w >> 2, wc = w & 3;   // 2 x 4 wave grid; wave tile 128x64

  const int nwg = gridDim.x;
  const int cpx = nwg >> 3;
  const int swz = (blockIdx.x & 7) * cpx + (blockIdx.x >> 3);
  const int nbn = N >> 8;
  const int bm = swz / nbn, bn = swz % nbn;

  f32x4 acc[8][4];
  const f32x4 z = {0.f, 0.f, 0.f, 0.f};
#pragma unroll
  for (int i = 0; i < 8; ++i)
#pragma unroll
    for (int j = 0; j < 4; ++j) acc[i][j] = z;

  // staging: inverse-swizzled global source, linear LDS dest (involution b^=((b>>7)&7)<<4)
  const int vs = (t >> 3) & 7;
  const int p0 = (t * 16) ^ (vs << 4);
  const int sm = p0 >> 6;
  const int sk = ((p0 >> 4) & 3) * 8;
  const unsigned short* gA0 = Xb + (size_t)(bm * 256 + sm) * K + sk;
  const unsigned short* gB0 = Wb + (size_t)(bn * 256 + sm) * K + sk;

#define STAGE(SLOT, KOFF)                                                   \
  { char* la_ = lds + (SLOT) * SLOT_BYTES;                                  \
    GLOAD_LDS16(gA0 + (KOFF),                   la_ + t * 16);              \
    GLOAD_LDS16(gA0 + (size_t)128 * K + (KOFF), la_ + 8192 + t * 16);       \
    GLOAD_LDS16(gB0 + (KOFF),                   la_ + 16384 + t * 16);      \
    GLOAD_LDS16(gB0 + (size_t)128 * K + (KOFF), la_ + 24576 + t * 16); }

  const int lane15 = lane & 15, ksl = lane >> 4;
  const int vr = (lane15 >> 1) & 7;
  const int abase = (((wr * 128 + lane15) * 64) + ksl * 16) ^ (vr << 4);
  const int bbase = 16384 + (((((wc * 64) + lane15) * 64) + ksl * 16) ^ (vr << 4));

#define READ_FRAGS(AF, BF, SLOT)                                            \
  { char* lp_ = lds + (SLOT) * SLOT_BYTES;                                  \
    _Pragma("unroll") for (int i = 0; i < 8; ++i)                           \
      AF[i] = *(const short8*)(lp_ + abase + i * 1024);                     \
    _Pragma("unroll") for (int j = 0; j < 4; ++j)                           \
      BF[j] = *(const short8*)(lp_ + bbase + j * 1024); }

#define MFMA_SET(AF, BF)                                                    \
  __builtin_amdgcn_s_setprio(1);                                            \
  _Pragma("unroll") for (int i = 0; i < 8; ++i)                             \
    _Pragma("unroll") for (int j = 0; j < 4; ++j)                           \
      acc[i][j] = __builtin_amdgcn_mfma_f32_16x16x32_bf16(AF[i], BF[j],     \
                                                          acc[i][j], 0, 0, 0); \
  __builtin_amdgcn_s_setprio(0);

// vmcnt(VM) + lgkmcnt(0): frag reads issued last iter are done (so MFMA set is
// ready AND the slot STAGE is about to overwrite has no pending readers), and
// the oldest staged tile has landed. Then barrier.
#define WAITBAR2(VM)                                                        \
  asm volatile("s_waitcnt vmcnt(" VM ") lgkmcnt(0)" ::: "memory");          \
  __builtin_amdgcn_s_barrier();                                             \
  __builtin_amdgcn_sched_barrier(0);

  short8 afA[8], bfA[4], afB[8], bfB[4];

  const int NT = K / TK;  // 64 (even, >= 8)

  STAGE(0, 0)
  STAGE(1, TK)
  STAGE(2, 2 * TK)
  WAITBAR2("8")
  READ_FRAGS(afA, bfA, 0)
  STAGE(3, 3 * TK)

  // bodies u = 1 .. NT-4 (each: drain tile u, stage u+3, read frags u, MFMA u-1)
  for (int u = 1; u <= NT - 4; u += 2) {
    WAITBAR2("8")
    STAGE((u + 3) & 3, (u + 3) * TK)
    READ_FRAGS(afB, bfB, u & 3)
    MFMA_SET(afA, bfA)

    WAITBAR2("8")
    STAGE((u + 4) & 3, (u + 4) * TK)
    READ_FRAGS(afA, bfA, (u + 1) & 3)
    MFMA_SET(afB, bfB)
  }

  // tails: u = NT-3, NT-2, NT-1 (no staging), then final MFMA
  WAITBAR2("8")
  READ_FRAGS(afB, bfB, (NT - 3) & 3)
  MFMA_SET(afA, bfA)

  WAITBAR2("4")
  READ_FRAGS(afA, bfA, (NT - 2) & 3)
  MFMA_SET(afB, bfB)

  WAITBAR2("0")
  READ_FRAGS(afB, bfB, (NT - 1) & 3)
  MFMA_SET(afA, bfA)

  MFMA_SET(afB, bfB)

  // epilogue: C/D layout col = lane&15, row = (lane>>4)*4 + q
  const int orow0 = bm * 256 + wr * 128 + ksl * 4;
  const int ocol0 = bn * 256 + wc * 64 + lane15;
#pragma unroll
  for (int i = 0; i < 8; ++i)
#pragma unroll
    for (int j = 0; j < 4; ++j) {
      size_t base = (size_t)(orow0 + i * 16) * N + (ocol0 + j * 16);
#pragma unroll
      for (int q = 0; q < 4; ++q) out[base + (size_t)q * N] = acc[i][j][q];
    }
}

extern "C" void kernel_launch(void* const* d_in, const int* in_sizes, int n_in,
                              void* d_out, int out_size, void* d_ws, size_t ws_size,
                              hipStream_t stream) {
  const float* x  = (const float*)d_in[0];
  const float* W  = (const float*)d_in[1];
  const float* Al = (const float*)d_in[2];
  const float* Bl = (const float*)d_in[3];
  float* out = (float*)d_out;

  const int K = 2048;
  const long long M = (long long)in_sizes[0] / K;  // 16384
  const int N = in_sizes[1] / K;                   // 2048
  const int R = in_sizes[2] / K;                   // 64

  unsigned short* xb   = (unsigned short*)d_ws;
  unsigned short* weff = xb + (size_t)M * K;       // ~76 MB of ws

  cvt_x_kernel<<<2048, 256, 0, stream>>>(x, xb, (long long)M * K);
  weff_kernel<<<dim3(K / 256, N / 16), 256, 0, stream>>>(W, Al, Bl, weff, N, K, R, 2.0f);
  gemm256_kernel<<<(N / 256) * (int)(M / 256), 512, 0, stream>>>(xb, weff, out, (int)M, N, K);
}

// Round 10
// 389.114 us; speedup vs baseline: 1.2678x; 1.0012x over previous
//
#include <hip/hip_runtime.h>
#include <hip/hip_bf16.h>

// out[M,N] = x @ (W + 2*B@A)^T.  M=16384, N=2048, K=2048, R=64.
// R10: m201-style 8-phase GEMM. 256^2 tile, BK=64, 2 LDS slots, K-half stage
// units, counted vmcnt(4) at phases 2&4, lgkmcnt(0)+sched_barrier before each
// 16-MFMA cluster, setprio, both-sides XOR swizzle, T1 XCD swizzle.

typedef short short8 __attribute__((ext_vector_type(8)));
typedef float f32x4 __attribute__((ext_vector_type(4)));

__device__ __forceinline__ unsigned short f2bf(float f) {
  unsigned u = __float_as_uint(f);
  u += 0x7fff + ((u >> 16) & 1);
  return (unsigned short)(u >> 16);
}

// ---------------- pass 1: x fp32 -> bf16 ----------------
__global__ __launch_bounds__(256) void cvt_x_kernel(const float* __restrict__ x,
                                                    unsigned short* __restrict__ xb,
                                                    long long n) {
  long long idx = ((long long)blockIdx.x * 256 + threadIdx.x) * 8;
  long long stride = (long long)gridDim.x * 256 * 8;
  for (; idx < n; idx += stride) {
    float4 v0 = *(const float4*)(x + idx);
    float4 v1 = *(const float4*)(x + idx + 4);
    short8 o;
    o[0] = (short)f2bf(v0.x); o[1] = (short)f2bf(v0.y);
    o[2] = (short)f2bf(v0.z); o[3] = (short)f2bf(v0.w);
    o[4] = (short)f2bf(v1.x); o[5] = (short)f2bf(v1.y);
    o[6] = (short)f2bf(v1.z); o[7] = (short)f2bf(v1.w);
    *(short8*)(xb + idx) = o;
  }
}

// ---------------- pass 2: W_eff = bf16(W + scaling * B@A) ----------------
__global__ __launch_bounds__(256) void weff_kernel(const float* __restrict__ W,
                                                   const float* __restrict__ Alora,
                                                   const float* __restrict__ Blora,
                                                   unsigned short* __restrict__ Weff,
                                                   int N, int K, int R, float scaling) {
  __shared__ float Bs[16][64];
  int t = threadIdx.x;
  int ob = blockIdx.y * 16;
  int i = blockIdx.x * 256 + t;
  for (int j = t; j < 16 * 64; j += 256)
    Bs[j >> 6][j & 63] = Blora[(ob + (j >> 6)) * R + (j & 63)];
  __syncthreads();
  float acc[16];
#pragma unroll
  for (int o = 0; o < 16; ++o) acc[o] = 0.f;
#pragma unroll 8
  for (int r = 0; r < 64; ++r) {
    float av = Alora[r * K + i];
#pragma unroll
    for (int o = 0; o < 16; ++o) acc[o] = fmaf(Bs[o][r], av, acc[o]);
  }
#pragma unroll
  for (int o = 0; o < 16; ++o) {
    float w = W[(size_t)(ob + o) * K + i];
    Weff[(size_t)(ob + o) * K + i] = f2bf(w + scaling * acc[o]);
  }
}

// ---------------- pass 3: 8-phase 256^2 bf16 GEMM ----------------
#define GLOAD_LDS16(g, l)                                                        \
  __builtin_amdgcn_global_load_lds((const __attribute__((address_space(1))) void*)(g), \
                                   (__attribute__((address_space(3))) void*)(l), 16, 0, 0)

// LDS: 2 slots x 64KB. Slot: A-ks0 [256][32] @0, A-ks1 @16384, B-ks0 @32768,
// B-ks1 @49152. Swizzle involution on unit-local byte addr: b ^= ((b>>7)&7)<<4.

__global__ __launch_bounds__(512, 2) void gemm8p_kernel(const unsigned short* __restrict__ Xb,
                                                        const unsigned short* __restrict__ Wb,
                                                        float* __restrict__ out,
                                                        int M, int N, int K) {
  __shared__ __align__(16) char lds[131072];

  const int t = threadIdx.x;
  const int lane = t & 63;
  const int w = t >> 6;
  const int wr = w >> 2, wc = w & 3;   // 2M x 4N waves; wave tile 128x64

  // T1: bijective XCD swizzle (nwg=512, %8==0)
  const int nwg = gridDim.x, cpx = nwg >> 3;
  const int swz = (blockIdx.x & 7) * cpx + (blockIdx.x >> 3);
  const int nbn = N >> 8;
  const int bm = swz / nbn, bn = swz % nbn;

  f32x4 acc[8][4];
  const f32x4 z = {0.f, 0.f, 0.f, 0.f};
#pragma unroll
  for (int i = 0; i < 8; ++i)
#pragma unroll
    for (int j = 0; j < 4; ++j) acc[i][j] = z;

  // stage source (inverse-swizzled): LDS[d] <- element[sw(d)], d = t*16 (+8192)
  const int srow = (t >> 2) ^ ((t >> 5) & 1);
  const int scol = ((t & 3) ^ ((t >> 3) & 3)) * 8;  // elems
  const unsigned short* gA = Xb + (size_t)(bm * 256 + srow) * K + scol;
  const unsigned short* gB = Wb + (size_t)(bn * 256 + srow) * K + scol;

  // frag read offsets (swizzled), unit-local
  const int lane15 = lane & 15, ksl = lane >> 4;
  const int key = ((lane15 >> 1) & 7) << 4;
  const int aRead = (((wr * 128 + lane15) * 64) + ksl * 16) ^ key;
  const int bRead = (((wc * 64 + lane15) * 64) + ksl * 16) ^ key;

  short8 af0, af1, af2, af3, bf0, bf1, bf2, bf3;

#define STG_A(NS, KSU, KOFF)                                                    \
  GLOAD_LDS16(gA + (KOFF), lds + (NS) * 65536 + (KSU) * 16384 + t * 16);        \
  GLOAD_LDS16(gA + (size_t)128 * K + (KOFF),                                    \
              lds + (NS) * 65536 + (KSU) * 16384 + 8192 + t * 16);
#define STG_B(NS, KSU, KOFF)                                                    \
  GLOAD_LDS16(gB + (KOFF), lds + (NS) * 65536 + 32768 + (KSU) * 16384 + t * 16);\
  GLOAD_LDS16(gB + (size_t)128 * K + (KOFF),                                    \
              lds + (NS) * 65536 + 32768 + (KSU) * 16384 + 8192 + t * 16);

#define RD_A(SLOT, KSU, MB) {                                                   \
    const char* p_ = lds + (SLOT) * 65536 + (KSU) * 16384 + aRead + (MB) * 1024;\
    af0 = *(const short8*)(p_);                                                 \
    af1 = *(const short8*)(p_ + 1024);                                          \
    af2 = *(const short8*)(p_ + 2048);                                          \
    af3 = *(const short8*)(p_ + 3072); }
#define RD_B(SLOT, KSU) {                                                       \
    const char* p_ = lds + (SLOT) * 65536 + 32768 + (KSU) * 16384 + bRead;      \
    bf0 = *(const short8*)(p_);                                                 \
    bf1 = *(const short8*)(p_ + 1024);                                          \
    bf2 = *(const short8*)(p_ + 2048);                                          \
    bf3 = *(const short8*)(p_ + 3072); }

#define MM4(AF, MI)                                                             \
  acc[MI][0] = __builtin_amdgcn_mfma_f32_16x16x32_bf16(AF, bf0, acc[MI][0], 0, 0, 0); \
  acc[MI][1] = __builtin_amdgcn_mfma_f32_16x16x32_bf16(AF, bf1, acc[MI][1], 0, 0, 0); \
  acc[MI][2] = __builtin_amdgcn_mfma_f32_16x16x32_bf16(AF, bf2, acc[MI][2], 0, 0, 0); \
  acc[MI][3] = __builtin_amdgcn_mfma_f32_16x16x32_bf16(AF, bf3, acc[MI][3], 0, 0, 0);

#define PH(SLOT, KSU, MB, RDB_STMT, STG_STMT, WAIT_STMT)                        \
  RD_A(SLOT, KSU, MB)                                                           \
  RDB_STMT                                                                      \
  STG_STMT                                                                      \
  WAIT_STMT                                                                     \
  __builtin_amdgcn_s_barrier();                                                 \
  asm volatile("s_waitcnt lgkmcnt(0)" ::: "memory");                            \
  __builtin_amdgcn_sched_barrier(0);                                            \
  __builtin_amdgcn_s_setprio(1);                                                \
  MM4(af0, (MB) + 0) MM4(af1, (MB) + 1) MM4(af2, (MB) + 2) MM4(af3, (MB) + 3)   \
  __builtin_amdgcn_s_setprio(0);                                                \
  __builtin_amdgcn_s_barrier();

#define VM4 asm volatile("s_waitcnt vmcnt(4)" ::: "memory");
#define VM0 asm volatile("s_waitcnt vmcnt(0)" ::: "memory");
#define NOP_

  // K-tile: 4 phases. Stage order for next tile: A-ks0, B-ks0, A-ks1, B-ks1.
  // vmcnt(4) at phases 2 & 4 guarantees (collectively, post-barrier) exactly
  // the units the following two phases read. Never 0 in main loop.
#define KTILE(SLOT, NS, KNEXT)                                                  \
  PH(SLOT, 0, 0, RD_B(SLOT, 0), STG_A(NS, 0, KNEXT), NOP_)                      \
  PH(SLOT, 0, 4, NOP_,          STG_B(NS, 0, KNEXT), VM4)                       \
  PH(SLOT, 1, 0, RD_B(SLOT, 1), STG_A(NS, 1, (KNEXT) + 32), NOP_)               \
  PH(SLOT, 1, 4, NOP_,          STG_B(NS, 1, (KNEXT) + 32), VM4)

#define KTILE_LAST(SLOT)                                                        \
  PH(SLOT, 0, 0, RD_B(SLOT, 0), NOP_, NOP_)                                     \
  PH(SLOT, 0, 4, NOP_,          NOP_, VM0)                                      \
  PH(SLOT, 1, 0, RD_B(SLOT, 1), NOP_, NOP_)                                     \
  PH(SLOT, 1, 4, NOP_,          NOP_, NOP_)

  // prologue: stage K-tile 0 fully into slot 0; drain its ks0 units.
  STG_A(0, 0, 0) STG_B(0, 0, 0) STG_A(0, 1, 32) STG_B(0, 1, 32)
  VM4
  __builtin_amdgcn_s_barrier();

  int kk = 64;  // k-base of the K-tile being staged
#pragma unroll 1
  for (int it = 0; it < 15; ++it) {   // tiles 0..29
    KTILE(0, 1, kk) kk += 64;
    KTILE(1, 0, kk) kk += 64;
  }
  KTILE(0, 1, kk)   // tile 30, stages tile 31 (kk = 1984)
  KTILE_LAST(1)     // tile 31

  // epilogue: C/D layout col = lane&15, row = (lane>>4)*4 + q
  const int orow0 = bm * 256 + wr * 128 + ksl * 4;
  const int ocol0 = bn * 256 + wc * 64 + lane15;
#pragma unroll
  for (int i = 0; i < 8; ++i)
#pragma unroll
    for (int j = 0; j < 4; ++j) {
      size_t base = (size_t)(orow0 + i * 16) * N + (ocol0 + j * 16);
#pragma unroll
      for (int q = 0; q < 4; ++q) out[base + (size_t)q * N] = acc[i][j][q];
    }
}

extern "C" void kernel_launch(void* const* d_in, const int* in_sizes, int n_in,
                              void* d_out, int out_size, void* d_ws, size_t ws_size,
                              hipStream_t stream) {
  const float* x  = (const float*)d_in[0];
  const float* W  = (const float*)d_in[1];
  const float* Al = (const float*)d_in[2];
  const float* Bl = (const float*)d_in[3];
  float* out = (float*)d_out;

  const int K = 2048;
  const long long M = (long long)in_sizes[0] / K;  // 16384
  const int N = in_sizes[1] / K;                   // 2048
  const int R = in_sizes[2] / K;                   // 64

  unsigned short* xb   = (unsigned short*)d_ws;
  unsigned short* weff = xb + (size_t)M * K;       // ~76 MB of ws

  cvt_x_kernel<<<2048, 256, 0, stream>>>(x, xb, (long long)M * K);
  weff_kernel<<<dim3(K / 256, N / 16), 256, 0, stream>>>(W, Al, Bl, weff, N, K, R, 2.0f);
  gemm8p_kernel<<<(N / 256) * (int)(M / 256), 512, 0, stream>>>(xb, weff, out, (int)M, N, K);
}